// Round 13
// baseline (217.551 us; speedup 1.0000x reference)
//
#include <hip/hip_runtime.h>
#include <cstddef>
#include <cstdint>

constexpr int N_NODES = 8192;
constexpr int E_EDGES = 262144;
constexpr int ET = E_EDGES + N_NODES;   // + self loops
constexpr int IN_DIM = 256;
constexpr int HID = 128;
constexpr int SLOTS = 128;              // per-dst bucket capacity (deg~Poisson(33))
constexpr float NEG_ATT = 0.2f;
constexpr float NEG_ACT = 0.02f;

typedef __attribute__((ext_vector_type(8))) short bf16x8;
typedef __attribute__((ext_vector_type(4))) float f32x4;

__device__ inline float lrelu(float v, float s) { return v >= 0.f ? v : s * v; }

#define GLD_LDS16(gaddr, laddr) \
    __builtin_amdgcn_global_load_lds( \
        (const __attribute__((address_space(1))) void*)(gaddr), \
        (__attribute__((address_space(3))) void*)(laddr), 16, 0, 0)

// ---------------- graph build: bucketed adjacency ----------------
__global__ void append_k(const int* __restrict__ ei, int* __restrict__ cnt,
                         int* __restrict__ csr) {
    int i = blockIdx.x * blockDim.x + threadIdx.x;
    if (i >= ET) return;
    int s, d;
    if (i < E_EDGES) { s = ei[i]; d = ei[E_EDGES + i]; }
    else             { s = i - E_EDGES; d = s; }
    int pos = atomicAdd(&cnt[d], 1);
    if (pos < SLOTS) csr[d * SLOTS + pos] = s;
}

// ---------------- h = x@W + attention logits (8 nodes / block) ----------------
// Layer-1 instance also zeroes cnt[] (blocks 0..63) for the subsequent append_k.
__global__ __launch_bounds__(128) void linear_alpha_k(
    const float* __restrict__ x, const float* __restrict__ W,
    const float* __restrict__ a_src, const float* __restrict__ a_dst,
    float* __restrict__ h, float* __restrict__ asrc, float* __restrict__ adst,
    int in_dim, int* __restrict__ cntz)
{
    __shared__ __align__(16) float xs[8][256];
    __shared__ float red[2][8][2];
    const int t = threadIdx.x;
    const int n0 = blockIdx.x * 8;
    if (cntz != nullptr && blockIdx.x < 64) cntz[blockIdx.x * 128 + t] = 0;
    for (int n = 0; n < 8; ++n)
        for (int i = t; i < in_dim; i += 128) xs[n][i] = x[(size_t)(n0 + n) * in_dim + i];
    __syncthreads();
    float acc[8] = {0.f,0.f,0.f,0.f,0.f,0.f,0.f,0.f};
    const float* Wc = W + t;
    for (int i4 = 0; i4 < in_dim / 4; ++i4) {
        float4 xv[8];
        #pragma unroll
        for (int n = 0; n < 8; ++n) xv[n] = *(const float4*)&xs[n][i4 * 4];
        float w0 = Wc[(i4 * 4 + 0) * HID];
        float w1 = Wc[(i4 * 4 + 1) * HID];
        float w2 = Wc[(i4 * 4 + 2) * HID];
        float w3 = Wc[(i4 * 4 + 3) * HID];
        #pragma unroll
        for (int n = 0; n < 8; ++n) {
            acc[n] = fmaf(xv[n].x, w0, acc[n]);
            acc[n] = fmaf(xv[n].y, w1, acc[n]);
            acc[n] = fmaf(xv[n].z, w2, acc[n]);
            acc[n] = fmaf(xv[n].w, w3, acc[n]);
        }
    }
    #pragma unroll
    for (int n = 0; n < 8; ++n) h[(size_t)(n0 + n) * HID + t] = acc[n];
    const float As = a_src[t], Ad = a_dst[t];
    const int wv_ = t >> 6;
    #pragma unroll
    for (int n = 0; n < 8; ++n) {
        float vs = acc[n] * As, vd = acc[n] * Ad;
        #pragma unroll
        for (int off = 32; off; off >>= 1) {
            vs += __shfl_down(vs, off, 64);
            vd += __shfl_down(vd, off, 64);
        }
        if ((t & 63) == 0) { red[wv_][n][0] = vs; red[wv_][n][1] = vd; }
    }
    __syncthreads();
    if (t < 8) {
        asrc[n0 + t] = red[0][t][0] + red[1][t][0];
        adst[n0 + t] = red[0][t][1] + red[1][t][1];
    }
}

// ------ fused softmax + aggregate + bias + leakyrelu: ONE WAVE PER DST --------
template<int EMIT>
__global__ __launch_bounds__(256) void gat_agg_k(
    const int* __restrict__ cnt, const int* __restrict__ csr,
    const float* __restrict__ asrc, const float* __restrict__ adst,
    const float* __restrict__ h, const float* __restrict__ bias,
    float* __restrict__ out, unsigned short* __restrict__ hi,
    unsigned short* __restrict__ lo)
{
    __shared__ float wbuf[4][SLOTS];
    __shared__ int   sbuf[4][SLOTS];
    const int wv = threadIdx.x >> 6, lane = threadIdx.x & 63;
    const int d = blockIdx.x * 4 + wv;
    int deg = cnt[d]; if (deg > SLOTS) deg = SLOTS;
    const float ad = adst[d];
    const int base = d * SLOTS;

    float sm = 0.f;
    for (int j = lane; j < deg; j += 64) {
        int s = csr[base + j];
        float e = asrc[s] + ad; e = e >= 0.f ? e : NEG_ATT * e;
        float ww = __expf(e);
        wbuf[wv][j] = ww; sbuf[wv][j] = s;
        sm += ww;
    }
    #pragma unroll
    for (int off = 32; off; off >>= 1) sm += __shfl_xor(sm, off, 64);
    const float inv = 1.f / sm;

    float ax = 0.f, ay = 0.f;
    #pragma unroll 4
    for (int j = 0; j < deg; ++j) {
        float ww = wbuf[wv][j];
        int   s  = sbuf[wv][j];
        const float2 hv = *(const float2*)(h + ((size_t)s << 7) + lane * 2);
        ax = fmaf(ww, hv.x, ax);
        ay = fmaf(ww, hv.y, ay);
    }
    const float2 bv = *(const float2*)(bias + lane * 2);
    float vx = lrelu(fmaf(ax, inv, bv.x), NEG_ACT);
    float vy = lrelu(fmaf(ay, inv, bv.y), NEG_ACT);

    if (EMIT) {
        uint32_t ux = __float_as_uint(vx);
        uint32_t rhx = (ux + 0x7FFFu + ((ux >> 16) & 1u)) & 0xFFFF0000u;
        float rx = vx - __uint_as_float(rhx);
        uint32_t urx = __float_as_uint(rx);
        uint32_t rlx = (urx + 0x7FFFu + ((urx >> 16) & 1u)) & 0xFFFF0000u;
        uint32_t uy = __float_as_uint(vy);
        uint32_t rhy = (uy + 0x7FFFu + ((uy >> 16) & 1u)) & 0xFFFF0000u;
        float ry = vy - __uint_as_float(rhy);
        uint32_t ury = __float_as_uint(ry);
        uint32_t rly = (ury + 0x7FFFu + ((ury >> 16) & 1u)) & 0xFFFF0000u;
        *(uint32_t*)(hi + ((size_t)d << 7) + lane * 2) = (rhx >> 16) | (rhy & 0xFFFF0000u);
        *(uint32_t*)(lo + ((size_t)d << 7) + lane * 2) = (rlx >> 16) | (rly & 0xFFFF0000u);
    } else {
        *(float2*)(out + ((size_t)d << 7) + lane * 2) = make_float2(vx, vy);
    }
}

// ---------------- C = A A^T via split-bf16 MFMA (hh + hl + lh), symmetric ----------
// ROUND-10 VERBATIM (hardware-proven 150 µs config). Launched TWICE this round
// as a timing decomposition experiment (bit-identical writes -> idempotent).
__global__ __launch_bounds__(256) void aat_mfma_k(
    const unsigned short* __restrict__ hi, const unsigned short* __restrict__ lo,
    float* __restrict__ C)
{
    __shared__ __align__(16) unsigned char smraw[65536];
    unsigned short* sm = (unsigned short*)smraw;   // 4 panels of 128x64 bf16
    const int t = threadIdx.x;
    const int lane = t & 63, wv = t >> 6;

    int b = blockIdx.x;
    int ti, tj;
    if (b < 2016) {                      // strict lower: ti in [1,63], tj < ti
        ti = (int)((__builtin_sqrtf(8.f * b + 1.f) + 1.f) * 0.5f);
        while (ti * (ti - 1) / 2 > b) --ti;
        while ((ti + 1) * ti / 2 <= b) ++ti;
        tj = b - ti * (ti - 1) / 2;
    } else {                             // diagonal (half work) scheduled last
        ti = b - 2016; tj = ti;
    }
    const int bi = ti * 128, bj = tj * 128;

    const int wi0 = (wv >> 1) * 64, wj0 = (wv & 1) * 64;
    const int lr = lane & 15, g = lane >> 4;

    f32x4 acc[4][4] = {};

    const unsigned short* gsrc[4] = { hi, lo, hi, lo };
    const int gbase[4] = { bi, bi, bj, bj };

    for (int ks = 0; ks < 2; ++ks) {
        if (ks) __syncthreads();
        #pragma unroll
        for (int arr = 0; arr < 4; ++arr) {
            #pragma unroll
            for (int call = 0; call < 4; ++call) {
                int r0 = wv * 32 + call * 8;            // wave-uniform
                int r = r0 + (lane >> 3);
                int chunk = (lane & 7) ^ (r & 7);
                const unsigned short* gp = gsrc[arr]
                    + (size_t)(gbase[arr] + r) * HID + ks * 64 + chunk * 8;
                unsigned short* lp = sm + arr * 8192 + r0 * 64;  // uniform base
                GLD_LDS16(gp, lp);
            }
        }
        __syncthreads();   // drains vmcnt

        #pragma unroll
        for (int kw = 0; kw < 2; ++kw) {
            bf16x8 ah[4], al[4], bh[4], bl[4];
            #pragma unroll
            for (int f = 0; f < 4; ++f) {
                int rA = wi0 + f * 16 + lr;
                int csA = (kw * 4 + g) ^ (rA & 7);
                ah[f] = *(const bf16x8*)(sm + 0 * 8192 + rA * 64 + csA * 8);
                al[f] = *(const bf16x8*)(sm + 1 * 8192 + rA * 64 + csA * 8);
                int rB = wj0 + f * 16 + lr;
                int csB = (kw * 4 + g) ^ (rB & 7);
                bh[f] = *(const bf16x8*)(sm + 2 * 8192 + rB * 64 + csB * 8);
                bl[f] = *(const bf16x8*)(sm + 3 * 8192 + rB * 64 + csB * 8);
            }
            #pragma unroll
            for (int fi = 0; fi < 4; ++fi)
                #pragma unroll
                for (int fj = 0; fj < 4; ++fj) {
                    acc[fi][fj] = __builtin_amdgcn_mfma_f32_16x16x32_bf16(ah[fi], bh[fj], acc[fi][fj], 0, 0, 0);
                    acc[fi][fj] = __builtin_amdgcn_mfma_f32_16x16x32_bf16(ah[fi], bl[fj], acc[fi][fj], 0, 0, 0);
                    acc[fi][fj] = __builtin_amdgcn_mfma_f32_16x16x32_bf16(al[fi], bh[fj], acc[fi][fj], 0, 0, 0);
                }
        }
    }

    __syncthreads();                       // panels dead for all waves
    float* T = (float*)smraw + wv * 4096;  // per-wave 64x64 f32, 16B-chunk XOR swizzle

    // ---- direct tile
    #pragma unroll
    for (int fi = 0; fi < 4; ++fi)
        #pragma unroll
        for (int fj = 0; fj < 4; ++fj)
            #pragma unroll
            for (int q = 0; q < 4; ++q) {
                int row = fi * 16 + g * 4 + q;
                int chunk = (fj * 4 + (lr >> 2)) ^ (row & 15);
                T[row * 64 + chunk * 4 + (lr & 3)] = acc[fi][fj][q];
            }
    #pragma unroll
    for (int it = 0; it < 16; ++it) {
        int row = it * 4 + g;
        f32x4 v = *(const f32x4*)(T + row * 64 + ((lr ^ (row & 15)) << 2));
        *(f32x4*)(C + (size_t)(bi + wi0 + row) * N_NODES + bj + wj0 + lr * 4) = v;
    }

    // ---- mirror tile (transpose)
    if (ti != tj) {
        #pragma unroll
        for (int fi = 0; fi < 4; ++fi)
            #pragma unroll
            for (int fj = 0; fj < 4; ++fj)
                *(f32x4*)(T + (fj * 16 + lr) * 64 + (((fi * 4 + g) ^ lr) << 2)) = acc[fi][fj];
        #pragma unroll
        for (int c4 = 0; c4 < 16; ++c4) {
            int c = c4 * 4 + g;
            f32x4 v = *(const f32x4*)(T + c * 64 + ((lr ^ (c & 15)) << 2));
            *(f32x4*)(C + (size_t)(bj + wj0 + c) * N_NODES + bi + wi0 + lr * 4) = v;
        }
    }
}

extern "C" void kernel_launch(void* const* d_in, const int* in_sizes, int n_in,
                              void* d_out, int out_size, void* d_ws, size_t ws_size,
                              hipStream_t stream)
{
    const float* x   = (const float*)d_in[0];
    const int*   ei  = (const int*)d_in[1];
    const float* W1  = (const float*)d_in[2];
    const float* a1s = (const float*)d_in[3];
    const float* a1d = (const float*)d_in[4];
    const float* b1  = (const float*)d_in[5];
    const float* W2  = (const float*)d_in[6];
    const float* a2s = (const float*)d_in[7];
    const float* a2d = (const float*)d_in[8];
    const float* b2  = (const float*)d_in[9];
    float* C = (float*)d_out;

    // workspace layout (~17 MB)
    char* base = (char*)d_ws;
    float* h    = (float*)base;                          // 4 MB
    float* act  = (float*)(base + (4u  << 20));          // 4 MB
    int*   csr  = (int*)  (base + (8u  << 20));          // 4 MB (8192 x 128)
    int*   cnt  = (int*)  (base + (12u << 20));          // 32 KB
    float* asrc = (float*)(base + (12u << 20) + (64u << 10));
    float* adst = (float*)(base + (12u << 20) + (96u << 10));
    unsigned short* hi = (unsigned short*)(base + (13u << 20)); // 2 MB
    unsigned short* lo = (unsigned short*)(base + (15u << 20)); // 2 MB

    const int eb = (ET + 255) / 256;

    // layer 1 linear (also zeroes cnt), then adjacency build, then aggregate
    linear_alpha_k<<<N_NODES / 8, 128, 0, stream>>>(x, W1, a1s, a1d, h, asrc, adst, IN_DIM, cnt);
    append_k<<<eb, 256, 0, stream>>>(ei, cnt, csr);
    gat_agg_k<0><<<N_NODES / 4, 256, 0, stream>>>(cnt, csr, asrc, adst, h, b1, act, nullptr, nullptr);
    // layer 2 (emits bf16 hi/lo directly)
    linear_alpha_k<<<N_NODES / 8, 128, 0, stream>>>(act, W2, a2s, a2d, h, asrc, adst, HID, nullptr);
    gat_agg_k<1><<<N_NODES / 4, 256, 0, stream>>>(cnt, csr, asrc, adst, h, b2, nullptr, hi, lo);

    // pred = act2 @ act2^T — launched TWICE (bit-identical writes) so that
    // dur - 150us isolates aat cost; revert to single launch next round.
    aat_mfma_k<<<64 * 65 / 2, 256, 0, stream>>>(hi, lo, C);
    aat_mfma_k<<<64 * 65 / 2, 256, 0, stream>>>(hi, lo, C);
}

// Round 14
// 153.227 us; speedup vs baseline: 1.4198x; 1.4198x over previous
//
#include <hip/hip_runtime.h>
#include <cstddef>
#include <cstdint>

constexpr int N_NODES = 8192;
constexpr int E_EDGES = 262144;
constexpr int ET = E_EDGES + N_NODES;   // + self loops
constexpr int IN_DIM = 256;
constexpr int HID = 128;
constexpr int SLOTS = 128;              // per-dst bucket capacity (deg~Poisson(33))
constexpr float NEG_ATT = 0.2f;
constexpr float NEG_ACT = 0.02f;

typedef __attribute__((ext_vector_type(8))) short bf16x8;
typedef __attribute__((ext_vector_type(4))) float f32x4;

__device__ inline float lrelu(float v, float s) { return v >= 0.f ? v : s * v; }

#define GLD_LDS16(gaddr, laddr) \
    __builtin_amdgcn_global_load_lds( \
        (const __attribute__((address_space(1))) void*)(gaddr), \
        (__attribute__((address_space(3))) void*)(laddr), 16, 0, 0)

// ---------------- graph build: bucketed adjacency ----------------
__global__ void append_k(const int* __restrict__ ei, int* __restrict__ cnt,
                         int* __restrict__ csr) {
    int i = blockIdx.x * blockDim.x + threadIdx.x;
    if (i >= ET) return;
    int s, d;
    if (i < E_EDGES) { s = ei[i]; d = ei[E_EDGES + i]; }
    else             { s = i - E_EDGES; d = s; }
    int pos = atomicAdd(&cnt[d], 1);
    if (pos < SLOTS) csr[d * SLOTS + pos] = s;
}

// ---------------- layer-1 linear: h = x@W1 + logits (8 nodes / block) ----------
// Also zeroes cnt[] (blocks 0..63) for the subsequent append_k.
__global__ __launch_bounds__(128) void linear_alpha_k(
    const float* __restrict__ x, const float* __restrict__ W,
    const float* __restrict__ a_src, const float* __restrict__ a_dst,
    float* __restrict__ h, float* __restrict__ asrc, float* __restrict__ adst,
    int in_dim, int* __restrict__ cntz)
{
    __shared__ __align__(16) float xs[8][256];
    __shared__ float red[2][8][2];
    const int t = threadIdx.x;
    const int n0 = blockIdx.x * 8;
    if (cntz != nullptr && blockIdx.x < 64) cntz[blockIdx.x * 128 + t] = 0;
    for (int n = 0; n < 8; ++n)
        for (int i = t; i < in_dim; i += 128) xs[n][i] = x[(size_t)(n0 + n) * in_dim + i];
    __syncthreads();
    float acc[8] = {0.f,0.f,0.f,0.f,0.f,0.f,0.f,0.f};
    const float* Wc = W + t;
    for (int i4 = 0; i4 < in_dim / 4; ++i4) {
        float4 xv[8];
        #pragma unroll
        for (int n = 0; n < 8; ++n) xv[n] = *(const float4*)&xs[n][i4 * 4];
        float w0 = Wc[(i4 * 4 + 0) * HID];
        float w1 = Wc[(i4 * 4 + 1) * HID];
        float w2 = Wc[(i4 * 4 + 2) * HID];
        float w3 = Wc[(i4 * 4 + 3) * HID];
        #pragma unroll
        for (int n = 0; n < 8; ++n) {
            acc[n] = fmaf(xv[n].x, w0, acc[n]);
            acc[n] = fmaf(xv[n].y, w1, acc[n]);
            acc[n] = fmaf(xv[n].z, w2, acc[n]);
            acc[n] = fmaf(xv[n].w, w3, acc[n]);
        }
    }
    #pragma unroll
    for (int n = 0; n < 8; ++n) h[(size_t)(n0 + n) * HID + t] = acc[n];
    const float As = a_src[t], Ad = a_dst[t];
    const int wv_ = t >> 6;
    #pragma unroll
    for (int n = 0; n < 8; ++n) {
        float vs = acc[n] * As, vd = acc[n] * Ad;
        #pragma unroll
        for (int off = 32; off; off >>= 1) {
            vs += __shfl_down(vs, off, 64);
            vd += __shfl_down(vd, off, 64);
        }
        if ((t & 63) == 0) { red[wv_][n][0] = vs; red[wv_][n][1] = vd; }
    }
    __syncthreads();
    if (t < 8) {
        asrc[n0 + t] = red[0][t][0] + red[1][t][0];
        adst[n0 + t] = red[0][t][1] + red[1][t][1];
    }
}

// ---- layer-1 aggregate + bias + lrelu + FUSED layer-2 linear (h2 = act1@W2) ----
// One wave per dst (round-10 agg verbatim). W2 staged chunk-wise into BLOCK LDS
// (8 chunks x 16 rows) so it's read once per block, not once per wave (round-9's
// mistake). act1 stays in registers; broadcast lane-by-lane via __shfl.
__global__ __launch_bounds__(256) void gat_agg_lin2_k(
    const int* __restrict__ cnt, const int* __restrict__ csr,
    const float* __restrict__ asrc, const float* __restrict__ adst,
    const float* __restrict__ h, const float* __restrict__ bias,
    const float* __restrict__ W2,
    const float* __restrict__ a2s, const float* __restrict__ a2d,
    float* __restrict__ h2, float* __restrict__ asrc2, float* __restrict__ adst2)
{
    __shared__ float wbuf[4][SLOTS];
    __shared__ int   sbuf[4][SLOTS];
    __shared__ __align__(16) float w2s[16][128];
    const int wv = threadIdx.x >> 6, lane = threadIdx.x & 63;
    const int d = blockIdx.x * 4 + wv;
    int deg = cnt[d]; if (deg > SLOTS) deg = SLOTS;
    const float ad = adst[d];
    const int base = d * SLOTS;

    float sm = 0.f;
    for (int j = lane; j < deg; j += 64) {
        int s = csr[base + j];
        float e = asrc[s] + ad; e = e >= 0.f ? e : NEG_ATT * e;
        float ww = __expf(e);
        wbuf[wv][j] = ww; sbuf[wv][j] = s;
        sm += ww;
    }
    #pragma unroll
    for (int off = 32; off; off >>= 1) sm += __shfl_xor(sm, off, 64);
    const float inv = 1.f / sm;

    float ax = 0.f, ay = 0.f;
    #pragma unroll 4
    for (int j = 0; j < deg; ++j) {
        float ww = wbuf[wv][j];
        int   s  = sbuf[wv][j];
        const float2 hv = *(const float2*)(h + ((size_t)s << 7) + lane * 2);
        ax = fmaf(ww, hv.x, ax);
        ay = fmaf(ww, hv.y, ay);
    }
    const float2 bv = *(const float2*)(bias + lane * 2);
    const float vx = lrelu(fmaf(ax, inv, bv.x), NEG_ACT);   // act1[d][2*lane]
    const float vy = lrelu(fmaf(ay, inv, bv.y), NEG_ACT);   // act1[d][2*lane+1]

    // ---- fused h2 = act1 @ W2, W2 staged per block in 16-row chunks ----
    float hx = 0.f, hy = 0.f;
    for (int c = 0; c < 8; ++c) {
        __syncthreads();                       // previous chunk consumed
        {
            int r  = threadIdx.x >> 4;         // 0..15
            int c0 = (threadIdx.x & 15) * 8;   // 0..120
            const float* src = W2 + (size_t)(c * 16 + r) * HID + c0;
            *(float4*)&w2s[r][c0]     = *(const float4*)(src);
            *(float4*)&w2s[r][c0 + 4] = *(const float4*)(src + 4);
        }
        __syncthreads();
        #pragma unroll
        for (int k = 0; k < 16; ++k) {         // global k = c*16 + k, ascending
            float a = (k & 1) ? __shfl(vy, c * 8 + (k >> 1), 64)
                              : __shfl(vx, c * 8 + (k >> 1), 64);
            const float2 w2v = *(const float2*)&w2s[k][lane * 2];
            hx = fmaf(a, w2v.x, hx);
            hy = fmaf(a, w2v.y, hy);
        }
    }
    *(float2*)(h2 + ((size_t)d << 7) + lane * 2) = make_float2(hx, hy);

    const float2 a2sv = *(const float2*)(a2s + lane * 2);
    const float2 a2dv = *(const float2*)(a2d + lane * 2);
    float ps = hx * a2sv.x + hy * a2sv.y;
    float pd = hx * a2dv.x + hy * a2dv.y;
    #pragma unroll
    for (int off = 32; off; off >>= 1) {
        ps += __shfl_xor(ps, off, 64);
        pd += __shfl_xor(pd, off, 64);
    }
    if (lane == 0) { asrc2[d] = ps; adst2[d] = pd; }
}

// ------ layer-2 aggregate + bias + lrelu, emits bf16 hi/lo (wave per dst) ------
__global__ __launch_bounds__(256) void gat_agg_emit_k(
    const int* __restrict__ cnt, const int* __restrict__ csr,
    const float* __restrict__ asrc, const float* __restrict__ adst,
    const float* __restrict__ h, const float* __restrict__ bias,
    unsigned short* __restrict__ hi, unsigned short* __restrict__ lo)
{
    __shared__ float wbuf[4][SLOTS];
    __shared__ int   sbuf[4][SLOTS];
    const int wv = threadIdx.x >> 6, lane = threadIdx.x & 63;
    const int d = blockIdx.x * 4 + wv;
    int deg = cnt[d]; if (deg > SLOTS) deg = SLOTS;
    const float ad = adst[d];
    const int base = d * SLOTS;

    float sm = 0.f;
    for (int j = lane; j < deg; j += 64) {
        int s = csr[base + j];
        float e = asrc[s] + ad; e = e >= 0.f ? e : NEG_ATT * e;
        float ww = __expf(e);
        wbuf[wv][j] = ww; sbuf[wv][j] = s;
        sm += ww;
    }
    #pragma unroll
    for (int off = 32; off; off >>= 1) sm += __shfl_xor(sm, off, 64);
    const float inv = 1.f / sm;

    float ax = 0.f, ay = 0.f;
    #pragma unroll 4
    for (int j = 0; j < deg; ++j) {
        float ww = wbuf[wv][j];
        int   s  = sbuf[wv][j];
        const float2 hv = *(const float2*)(h + ((size_t)s << 7) + lane * 2);
        ax = fmaf(ww, hv.x, ax);
        ay = fmaf(ww, hv.y, ay);
    }
    const float2 bv = *(const float2*)(bias + lane * 2);
    float vx = lrelu(fmaf(ax, inv, bv.x), NEG_ACT);
    float vy = lrelu(fmaf(ay, inv, bv.y), NEG_ACT);

    uint32_t ux = __float_as_uint(vx);
    uint32_t rhx = (ux + 0x7FFFu + ((ux >> 16) & 1u)) & 0xFFFF0000u;
    float rx = vx - __uint_as_float(rhx);
    uint32_t urx = __float_as_uint(rx);
    uint32_t rlx = (urx + 0x7FFFu + ((urx >> 16) & 1u)) & 0xFFFF0000u;
    uint32_t uy = __float_as_uint(vy);
    uint32_t rhy = (uy + 0x7FFFu + ((uy >> 16) & 1u)) & 0xFFFF0000u;
    float ry = vy - __uint_as_float(rhy);
    uint32_t ury = __float_as_uint(ry);
    uint32_t rly = (ury + 0x7FFFu + ((ury >> 16) & 1u)) & 0xFFFF0000u;
    *(uint32_t*)(hi + ((size_t)d << 7) + lane * 2) = (rhx >> 16) | (rhy & 0xFFFF0000u);
    *(uint32_t*)(lo + ((size_t)d << 7) + lane * 2) = (rlx >> 16) | (rly & 0xFFFF0000u);
}

// ---------------- C = A A^T via split-bf16 MFMA (hh + hl + lh), symmetric ----------
// ROUND-10 VERBATIM (hardware-proven): BK=64 global_load_lds staging,
// pre-swizzled source + linear LDS dest, LDS-bounced plain full-line stores,
// strict-lower pairs first / diagonals last.
__global__ __launch_bounds__(256) void aat_mfma_k(
    const unsigned short* __restrict__ hi, const unsigned short* __restrict__ lo,
    float* __restrict__ C)
{
    __shared__ __align__(16) unsigned char smraw[65536];
    unsigned short* sm = (unsigned short*)smraw;   // 4 panels of 128x64 bf16
    const int t = threadIdx.x;
    const int lane = t & 63, wv = t >> 6;

    int b = blockIdx.x;
    int ti, tj;
    if (b < 2016) {                      // strict lower: ti in [1,63], tj < ti
        ti = (int)((__builtin_sqrtf(8.f * b + 1.f) + 1.f) * 0.5f);
        while (ti * (ti - 1) / 2 > b) --ti;
        while ((ti + 1) * ti / 2 <= b) ++ti;
        tj = b - ti * (ti - 1) / 2;
    } else {                             // diagonal (half work) scheduled last
        ti = b - 2016; tj = ti;
    }
    const int bi = ti * 128, bj = tj * 128;

    const int wi0 = (wv >> 1) * 64, wj0 = (wv & 1) * 64;
    const int lr = lane & 15, g = lane >> 4;

    f32x4 acc[4][4] = {};

    const unsigned short* gsrc[4] = { hi, lo, hi, lo };
    const int gbase[4] = { bi, bi, bj, bj };

    for (int ks = 0; ks < 2; ++ks) {
        if (ks) __syncthreads();
        #pragma unroll
        for (int arr = 0; arr < 4; ++arr) {
            #pragma unroll
            for (int call = 0; call < 4; ++call) {
                int r0 = wv * 32 + call * 8;            // wave-uniform
                int r = r0 + (lane >> 3);
                int chunk = (lane & 7) ^ (r & 7);
                const unsigned short* gp = gsrc[arr]
                    + (size_t)(gbase[arr] + r) * HID + ks * 64 + chunk * 8;
                unsigned short* lp = sm + arr * 8192 + r0 * 64;  // uniform base
                GLD_LDS16(gp, lp);
            }
        }
        __syncthreads();   // drains vmcnt

        #pragma unroll
        for (int kw = 0; kw < 2; ++kw) {
            bf16x8 ah[4], al[4], bh[4], bl[4];
            #pragma unroll
            for (int f = 0; f < 4; ++f) {
                int rA = wi0 + f * 16 + lr;
                int csA = (kw * 4 + g) ^ (rA & 7);
                ah[f] = *(const bf16x8*)(sm + 0 * 8192 + rA * 64 + csA * 8);
                al[f] = *(const bf16x8*)(sm + 1 * 8192 + rA * 64 + csA * 8);
                int rB = wj0 + f * 16 + lr;
                int csB = (kw * 4 + g) ^ (rB & 7);
                bh[f] = *(const bf16x8*)(sm + 2 * 8192 + rB * 64 + csB * 8);
                bl[f] = *(const bf16x8*)(sm + 3 * 8192 + rB * 64 + csB * 8);
            }
            #pragma unroll
            for (int fi = 0; fi < 4; ++fi)
                #pragma unroll
                for (int fj = 0; fj < 4; ++fj) {
                    acc[fi][fj] = __builtin_amdgcn_mfma_f32_16x16x32_bf16(ah[fi], bh[fj], acc[fi][fj], 0, 0, 0);
                    acc[fi][fj] = __builtin_amdgcn_mfma_f32_16x16x32_bf16(ah[fi], bl[fj], acc[fi][fj], 0, 0, 0);
                    acc[fi][fj] = __builtin_amdgcn_mfma_f32_16x16x32_bf16(al[fi], bh[fj], acc[fi][fj], 0, 0, 0);
                }
        }
    }

    __syncthreads();                       // panels dead for all waves
    float* T = (float*)smraw + wv * 4096;  // per-wave 64x64 f32, 16B-chunk XOR swizzle

    // ---- direct tile
    #pragma unroll
    for (int fi = 0; fi < 4; ++fi)
        #pragma unroll
        for (int fj = 0; fj < 4; ++fj)
            #pragma unroll
            for (int q = 0; q < 4; ++q) {
                int row = fi * 16 + g * 4 + q;
                int chunk = (fj * 4 + (lr >> 2)) ^ (row & 15);
                T[row * 64 + chunk * 4 + (lr & 3)] = acc[fi][fj][q];
            }
    #pragma unroll
    for (int it = 0; it < 16; ++it) {
        int row = it * 4 + g;
        f32x4 v = *(const f32x4*)(T + row * 64 + ((lr ^ (row & 15)) << 2));
        *(f32x4*)(C + (size_t)(bi + wi0 + row) * N_NODES + bj + wj0 + lr * 4) = v;
    }

    // ---- mirror tile (transpose)
    if (ti != tj) {
        #pragma unroll
        for (int fi = 0; fi < 4; ++fi)
            #pragma unroll
            for (int fj = 0; fj < 4; ++fj)
                *(f32x4*)(T + (fj * 16 + lr) * 64 + (((fi * 4 + g) ^ lr) << 2)) = acc[fi][fj];
        #pragma unroll
        for (int c4 = 0; c4 < 16; ++c4) {
            int c = c4 * 4 + g;
            f32x4 v = *(const f32x4*)(T + c * 64 + ((lr ^ (c & 15)) << 2));
            *(f32x4*)(C + (size_t)(bj + wj0 + c) * N_NODES + bi + wi0 + lr * 4) = v;
        }
    }
}

extern "C" void kernel_launch(void* const* d_in, const int* in_sizes, int n_in,
                              void* d_out, int out_size, void* d_ws, size_t ws_size,
                              hipStream_t stream)
{
    const float* x   = (const float*)d_in[0];
    const int*   ei  = (const int*)d_in[1];
    const float* W1  = (const float*)d_in[2];
    const float* a1s = (const float*)d_in[3];
    const float* a1d = (const float*)d_in[4];
    const float* b1  = (const float*)d_in[5];
    const float* W2  = (const float*)d_in[6];
    const float* a2s = (const float*)d_in[7];
    const float* a2d = (const float*)d_in[8];
    const float* b2  = (const float*)d_in[9];
    float* C = (float*)d_out;

    // workspace layout (~17 MB)
    char* base = (char*)d_ws;
    float* h     = (float*)base;                          // 4 MB (layer-1 h)
    float* h2    = (float*)(base + (4u  << 20));          // 4 MB (layer-2 h)
    int*   csr   = (int*)  (base + (8u  << 20));          // 4 MB (8192 x 128)
    int*   cnt   = (int*)  (base + (12u << 20));          // 32 KB
    float* asrc  = (float*)(base + (12u << 20) + (64u  << 10));
    float* adst  = (float*)(base + (12u << 20) + (96u  << 10));
    float* asrc2 = (float*)(base + (12u << 20) + (128u << 10));
    float* adst2 = (float*)(base + (12u << 20) + (160u << 10));
    unsigned short* hi = (unsigned short*)(base + (13u << 20)); // 2 MB
    unsigned short* lo = (unsigned short*)(base + (15u << 20)); // 2 MB

    const int eb = (ET + 255) / 256;

    // layer-1 linear (also zeroes cnt), adjacency build
    linear_alpha_k<<<N_NODES / 8, 128, 0, stream>>>(x, W1, a1s, a1d, h, asrc, adst, IN_DIM, cnt);
    append_k<<<eb, 256, 0, stream>>>(ei, cnt, csr);
    // layer-1 aggregate + fused layer-2 linear (block-staged W2)
    gat_agg_lin2_k<<<N_NODES / 4, 256, 0, stream>>>(cnt, csr, asrc, adst, h, b1,
                                                    W2, a2s, a2d, h2, asrc2, adst2);
    // layer-2 aggregate (emits bf16 hi/lo)
    gat_agg_emit_k<<<N_NODES / 4, 256, 0, stream>>>(cnt, csr, asrc2, adst2, h2, b2, hi, lo);
    // pred = act2 @ act2^T (round-10 aat, single launch)
    aat_mfma_k<<<64 * 65 / 2, 256, 0, stream>>>(hi, lo, C);
}

// Round 15
// 136.753 us; speedup vs baseline: 1.5908x; 1.1205x over previous
//
#include <hip/hip_runtime.h>
#include <cstddef>
#include <cstdint>

constexpr int N_NODES = 8192;
constexpr int E_EDGES = 262144;
constexpr int ET = E_EDGES + N_NODES;   // + self loops
constexpr int IN_DIM = 256;
constexpr int HID = 128;
constexpr int SLOTS = 128;              // per-dst bucket capacity (deg~Poisson(33))
constexpr float NEG_ATT = 0.2f;
constexpr float NEG_ACT = 0.02f;

typedef __attribute__((ext_vector_type(8))) short bf16x8;
typedef __attribute__((ext_vector_type(4))) float f32x4;

__device__ inline float lrelu(float v, float s) { return v >= 0.f ? v : s * v; }

#define GLD_LDS16(gaddr, laddr) \
    __builtin_amdgcn_global_load_lds( \
        (const __attribute__((address_space(1))) void*)(gaddr), \
        (__attribute__((address_space(3))) void*)(laddr), 16, 0, 0)

// ---------------- graph build: bucketed adjacency ----------------
__global__ void append_k(const int* __restrict__ ei, int* __restrict__ cnt,
                         int* __restrict__ csr) {
    int i = blockIdx.x * blockDim.x + threadIdx.x;
    if (i >= ET) return;
    int s, d;
    if (i < E_EDGES) { s = ei[i]; d = ei[E_EDGES + i]; }
    else             { s = i - E_EDGES; d = s; }
    int pos = atomicAdd(&cnt[d], 1);
    if (pos < SLOTS) csr[d * SLOTS + pos] = s;
}

// ---------------- h = x@W + attention logits (8 nodes / block) ----------------
// Layer-1 instance also zeroes cnt[] (blocks 0..63) for the subsequent append_k.
__global__ __launch_bounds__(128) void linear_alpha_k(
    const float* __restrict__ x, const float* __restrict__ W,
    const float* __restrict__ a_src, const float* __restrict__ a_dst,
    float* __restrict__ h, float* __restrict__ asrc, float* __restrict__ adst,
    int in_dim, int* __restrict__ cntz)
{
    __shared__ __align__(16) float xs[8][256];
    __shared__ float red[2][8][2];
    const int t = threadIdx.x;
    const int n0 = blockIdx.x * 8;
    if (cntz != nullptr && blockIdx.x < 64) cntz[blockIdx.x * 128 + t] = 0;
    for (int n = 0; n < 8; ++n)
        for (int i = t; i < in_dim; i += 128) xs[n][i] = x[(size_t)(n0 + n) * in_dim + i];
    __syncthreads();
    float acc[8] = {0.f,0.f,0.f,0.f,0.f,0.f,0.f,0.f};
    const float* Wc = W + t;
    for (int i4 = 0; i4 < in_dim / 4; ++i4) {
        float4 xv[8];
        #pragma unroll
        for (int n = 0; n < 8; ++n) xv[n] = *(const float4*)&xs[n][i4 * 4];
        float w0 = Wc[(i4 * 4 + 0) * HID];
        float w1 = Wc[(i4 * 4 + 1) * HID];
        float w2 = Wc[(i4 * 4 + 2) * HID];
        float w3 = Wc[(i4 * 4 + 3) * HID];
        #pragma unroll
        for (int n = 0; n < 8; ++n) {
            acc[n] = fmaf(xv[n].x, w0, acc[n]);
            acc[n] = fmaf(xv[n].y, w1, acc[n]);
            acc[n] = fmaf(xv[n].z, w2, acc[n]);
            acc[n] = fmaf(xv[n].w, w3, acc[n]);
        }
    }
    #pragma unroll
    for (int n = 0; n < 8; ++n) h[(size_t)(n0 + n) * HID + t] = acc[n];
    const float As = a_src[t], Ad = a_dst[t];
    const int wv_ = t >> 6;
    #pragma unroll
    for (int n = 0; n < 8; ++n) {
        float vs = acc[n] * As, vd = acc[n] * Ad;
        #pragma unroll
        for (int off = 32; off; off >>= 1) {
            vs += __shfl_down(vs, off, 64);
            vd += __shfl_down(vd, off, 64);
        }
        if ((t & 63) == 0) { red[wv_][n][0] = vs; red[wv_][n][1] = vd; }
    }
    __syncthreads();
    if (t < 8) {
        asrc[n0 + t] = red[0][t][0] + red[1][t][0];
        adst[n0 + t] = red[0][t][1] + red[1][t][1];
    }
}

// ------ fused softmax + aggregate + bias + leakyrelu: ONE WAVE PER DST --------
// EMIT=1 writes bf16 hi (RNE) only — the AA^T GEMM is hh-only this round.
template<int EMIT>
__global__ __launch_bounds__(256) void gat_agg_k(
    const int* __restrict__ cnt, const int* __restrict__ csr,
    const float* __restrict__ asrc, const float* __restrict__ adst,
    const float* __restrict__ h, const float* __restrict__ bias,
    float* __restrict__ out, unsigned short* __restrict__ hi)
{
    __shared__ float wbuf[4][SLOTS];
    __shared__ int   sbuf[4][SLOTS];
    const int wv = threadIdx.x >> 6, lane = threadIdx.x & 63;
    const int d = blockIdx.x * 4 + wv;
    int deg = cnt[d]; if (deg > SLOTS) deg = SLOTS;
    const float ad = adst[d];
    const int base = d * SLOTS;

    float sm = 0.f;
    for (int j = lane; j < deg; j += 64) {
        int s = csr[base + j];
        float e = asrc[s] + ad; e = e >= 0.f ? e : NEG_ATT * e;
        float ww = __expf(e);
        wbuf[wv][j] = ww; sbuf[wv][j] = s;
        sm += ww;
    }
    #pragma unroll
    for (int off = 32; off; off >>= 1) sm += __shfl_xor(sm, off, 64);
    const float inv = 1.f / sm;

    float ax = 0.f, ay = 0.f;
    #pragma unroll 4
    for (int j = 0; j < deg; ++j) {
        float ww = wbuf[wv][j];
        int   s  = sbuf[wv][j];
        const float2 hv = *(const float2*)(h + ((size_t)s << 7) + lane * 2);
        ax = fmaf(ww, hv.x, ax);
        ay = fmaf(ww, hv.y, ay);
    }
    const float2 bv = *(const float2*)(bias + lane * 2);
    float vx = lrelu(fmaf(ax, inv, bv.x), NEG_ACT);
    float vy = lrelu(fmaf(ay, inv, bv.y), NEG_ACT);

    if (EMIT) {
        uint32_t ux = __float_as_uint(vx);
        uint32_t rhx = (ux + 0x7FFFu + ((ux >> 16) & 1u)) & 0xFFFF0000u;   // RNE
        uint32_t uy = __float_as_uint(vy);
        uint32_t rhy = (uy + 0x7FFFu + ((uy >> 16) & 1u)) & 0xFFFF0000u;
        *(uint32_t*)(hi + ((size_t)d << 7) + lane * 2) = (rhx >> 16) | (rhy & 0xFFFF0000u);
    } else {
        *(float2*)(out + ((size_t)d << 7) + lane * 2) = make_float2(vx, vy);
    }
}

// ---------------- C = A A^T, hh-only bf16 MFMA, symmetric ----------------
// Round-10 structure verbatim with the lo panels/MFMAs deleted:
// 2 panels (hi_A, hi_B) = 32 KB staged per K-step; 64 MFMA/block (was 192);
// LDS-bounced plain full-line stores; strict-lower pairs first, diagonals last.
// Error budget: dropped hl+lh corrections are |C|*2^-8 with random signs
// (~1e-4 expected) on top of the stable 4.88e-4 — threshold is 1.99e-3.
__global__ __launch_bounds__(256) void aat_mfma_k(
    const unsigned short* __restrict__ hi, float* __restrict__ C)
{
    __shared__ __align__(16) unsigned char smraw[65536];
    unsigned short* sm = (unsigned short*)smraw;   // 2 panels of 128x64 bf16 (32 KB)
    const int t = threadIdx.x;
    const int lane = t & 63, wv = t >> 6;

    int b = blockIdx.x;
    int ti, tj;
    if (b < 2016) {                      // strict lower: ti in [1,63], tj < ti
        ti = (int)((__builtin_sqrtf(8.f * b + 1.f) + 1.f) * 0.5f);
        while (ti * (ti - 1) / 2 > b) --ti;
        while ((ti + 1) * ti / 2 <= b) ++ti;
        tj = b - ti * (ti - 1) / 2;
    } else {                             // diagonal (half work) scheduled last
        ti = b - 2016; tj = ti;
    }
    const int bi = ti * 128, bj = tj * 128;

    const int wi0 = (wv >> 1) * 64, wj0 = (wv & 1) * 64;
    const int lr = lane & 15, g = lane >> 4;

    f32x4 acc[4][4] = {};

    const int gbase[2] = { bi, bj };

    for (int ks = 0; ks < 2; ++ks) {
        if (ks) __syncthreads();
        #pragma unroll
        for (int arr = 0; arr < 2; ++arr) {
            #pragma unroll
            for (int call = 0; call < 4; ++call) {
                int r0 = wv * 32 + call * 8;            // wave-uniform
                int r = r0 + (lane >> 3);
                int chunk = (lane & 7) ^ (r & 7);
                const unsigned short* gp = hi
                    + (size_t)(gbase[arr] + r) * HID + ks * 64 + chunk * 8;
                unsigned short* lp = sm + arr * 8192 + r0 * 64;  // uniform base
                GLD_LDS16(gp, lp);
            }
        }
        __syncthreads();   // drains vmcnt

        #pragma unroll
        for (int kw = 0; kw < 2; ++kw) {
            bf16x8 ah[4], bh[4];
            #pragma unroll
            for (int f = 0; f < 4; ++f) {
                int rA = wi0 + f * 16 + lr;
                int csA = (kw * 4 + g) ^ (rA & 7);
                ah[f] = *(const bf16x8*)(sm + 0 * 8192 + rA * 64 + csA * 8);
                int rB = wj0 + f * 16 + lr;
                int csB = (kw * 4 + g) ^ (rB & 7);
                bh[f] = *(const bf16x8*)(sm + 1 * 8192 + rB * 64 + csB * 8);
            }
            #pragma unroll
            for (int fi = 0; fi < 4; ++fi)
                #pragma unroll
                for (int fj = 0; fj < 4; ++fj)
                    acc[fi][fj] = __builtin_amdgcn_mfma_f32_16x16x32_bf16(ah[fi], bh[fj], acc[fi][fj], 0, 0, 0);
        }
    }

    __syncthreads();                       // panels dead for all waves
    float* T = (float*)smraw + wv * 4096;  // per-wave 64x64 f32, 16B-chunk XOR swizzle

    // ---- direct tile
    #pragma unroll
    for (int fi = 0; fi < 4; ++fi)
        #pragma unroll
        for (int fj = 0; fj < 4; ++fj)
            #pragma unroll
            for (int q = 0; q < 4; ++q) {
                int row = fi * 16 + g * 4 + q;
                int chunk = (fj * 4 + (lr >> 2)) ^ (row & 15);
                T[row * 64 + chunk * 4 + (lr & 3)] = acc[fi][fj][q];
            }
    #pragma unroll
    for (int it = 0; it < 16; ++it) {
        int row = it * 4 + g;
        f32x4 v = *(const f32x4*)(T + row * 64 + ((lr ^ (row & 15)) << 2));
        *(f32x4*)(C + (size_t)(bi + wi0 + row) * N_NODES + bj + wj0 + lr * 4) = v;
    }

    // ---- mirror tile (transpose)
    if (ti != tj) {
        #pragma unroll
        for (int fi = 0; fi < 4; ++fi)
            #pragma unroll
            for (int fj = 0; fj < 4; ++fj)
                *(f32x4*)(T + (fj * 16 + lr) * 64 + (((fi * 4 + g) ^ lr) << 2)) = acc[fi][fj];
        #pragma unroll
        for (int c4 = 0; c4 < 16; ++c4) {
            int c = c4 * 4 + g;
            f32x4 v = *(const f32x4*)(T + c * 64 + ((lr ^ (c & 15)) << 2));
            *(f32x4*)(C + (size_t)(bj + wj0 + c) * N_NODES + bi + wi0 + lr * 4) = v;
        }
    }
}

extern "C" void kernel_launch(void* const* d_in, const int* in_sizes, int n_in,
                              void* d_out, int out_size, void* d_ws, size_t ws_size,
                              hipStream_t stream)
{
    const float* x   = (const float*)d_in[0];
    const int*   ei  = (const int*)d_in[1];
    const float* W1  = (const float*)d_in[2];
    const float* a1s = (const float*)d_in[3];
    const float* a1d = (const float*)d_in[4];
    const float* b1  = (const float*)d_in[5];
    const float* W2  = (const float*)d_in[6];
    const float* a2s = (const float*)d_in[7];
    const float* a2d = (const float*)d_in[8];
    const float* b2  = (const float*)d_in[9];
    float* C = (float*)d_out;

    // workspace layout (~15 MB)
    char* base = (char*)d_ws;
    float* h    = (float*)base;                          // 4 MB
    float* act  = (float*)(base + (4u  << 20));          // 4 MB
    int*   csr  = (int*)  (base + (8u  << 20));          // 4 MB (8192 x 128)
    int*   cnt  = (int*)  (base + (12u << 20));          // 32 KB
    float* asrc = (float*)(base + (12u << 20) + (64u << 10));
    float* adst = (float*)(base + (12u << 20) + (96u << 10));
    unsigned short* hi = (unsigned short*)(base + (13u << 20)); // 2 MB

    const int eb = (ET + 255) / 256;

    // layer 1 linear (also zeroes cnt), then adjacency build, then aggregate
    linear_alpha_k<<<N_NODES / 8, 128, 0, stream>>>(x, W1, a1s, a1d, h, asrc, adst, IN_DIM, cnt);
    append_k<<<eb, 256, 0, stream>>>(ei, cnt, csr);
    gat_agg_k<0><<<N_NODES / 4, 256, 0, stream>>>(cnt, csr, asrc, adst, h, b1, act, nullptr);
    // layer 2 (emits bf16 hi directly)
    linear_alpha_k<<<N_NODES / 8, 128, 0, stream>>>(act, W2, a2s, a2d, h, asrc, adst, HID, nullptr);
    gat_agg_k<1><<<N_NODES / 4, 256, 0, stream>>>(cnt, csr, asrc, adst, h, b2, nullptr, hi);

    // pred = act2 @ act2^T (hh-only): strict-lower pairs first, diagonals last
    aat_mfma_k<<<64 * 65 / 2, 256, 0, stream>>>(hi, C);
}

// Round 16
// 134.362 us; speedup vs baseline: 1.6191x; 1.0178x over previous
//
#include <hip/hip_runtime.h>
#include <cstddef>
#include <cstdint>

constexpr int N_NODES = 8192;
constexpr int E_EDGES = 262144;
constexpr int ET = E_EDGES + N_NODES;   // + self loops
constexpr int IN_DIM = 256;
constexpr int HID = 128;
constexpr int SLOTS = 128;              // per-dst bucket capacity (deg~Poisson(33))
constexpr float NEG_ATT = 0.2f;
constexpr float NEG_ACT = 0.02f;

typedef __attribute__((ext_vector_type(8))) short bf16x8;
typedef __attribute__((ext_vector_type(4))) float f32x4;

__device__ inline float lrelu(float v, float s) { return v >= 0.f ? v : s * v; }

#define GLD_LDS16(gaddr, laddr) \
    __builtin_amdgcn_global_load_lds( \
        (const __attribute__((address_space(1))) void*)(gaddr), \
        (__attribute__((address_space(3))) void*)(laddr), 16, 0, 0)

// ---------------- graph build: bucketed adjacency ----------------
__global__ void append_k(const int* __restrict__ ei, int* __restrict__ cnt,
                         int* __restrict__ csr) {
    int i = blockIdx.x * blockDim.x + threadIdx.x;
    if (i >= ET) return;
    int s, d;
    if (i < E_EDGES) { s = ei[i]; d = ei[E_EDGES + i]; }
    else             { s = i - E_EDGES; d = s; }
    int pos = atomicAdd(&cnt[d], 1);
    if (pos < SLOTS) csr[d * SLOTS + pos] = s;
}

// ---------------- h = x@W + attention logits (8 nodes / block) ----------------
// Layer-1 instance also zeroes cnt[] (blocks 0..63) for the subsequent append_k.
__global__ __launch_bounds__(128) void linear_alpha_k(
    const float* __restrict__ x, const float* __restrict__ W,
    const float* __restrict__ a_src, const float* __restrict__ a_dst,
    float* __restrict__ h, float* __restrict__ asrc, float* __restrict__ adst,
    int in_dim, int* __restrict__ cntz)
{
    __shared__ __align__(16) float xs[8][256];
    __shared__ float red[2][8][2];
    const int t = threadIdx.x;
    const int n0 = blockIdx.x * 8;
    if (cntz != nullptr && blockIdx.x < 64) cntz[blockIdx.x * 128 + t] = 0;
    for (int n = 0; n < 8; ++n)
        for (int i = t; i < in_dim; i += 128) xs[n][i] = x[(size_t)(n0 + n) * in_dim + i];
    __syncthreads();
    float acc[8] = {0.f,0.f,0.f,0.f,0.f,0.f,0.f,0.f};
    const float* Wc = W + t;
    for (int i4 = 0; i4 < in_dim / 4; ++i4) {
        float4 xv[8];
        #pragma unroll
        for (int n = 0; n < 8; ++n) xv[n] = *(const float4*)&xs[n][i4 * 4];
        float w0 = Wc[(i4 * 4 + 0) * HID];
        float w1 = Wc[(i4 * 4 + 1) * HID];
        float w2 = Wc[(i4 * 4 + 2) * HID];
        float w3 = Wc[(i4 * 4 + 3) * HID];
        #pragma unroll
        for (int n = 0; n < 8; ++n) {
            acc[n] = fmaf(xv[n].x, w0, acc[n]);
            acc[n] = fmaf(xv[n].y, w1, acc[n]);
            acc[n] = fmaf(xv[n].z, w2, acc[n]);
            acc[n] = fmaf(xv[n].w, w3, acc[n]);
        }
    }
    #pragma unroll
    for (int n = 0; n < 8; ++n) h[(size_t)(n0 + n) * HID + t] = acc[n];
    const float As = a_src[t], Ad = a_dst[t];
    const int wv_ = t >> 6;
    #pragma unroll
    for (int n = 0; n < 8; ++n) {
        float vs = acc[n] * As, vd = acc[n] * Ad;
        #pragma unroll
        for (int off = 32; off; off >>= 1) {
            vs += __shfl_down(vs, off, 64);
            vd += __shfl_down(vd, off, 64);
        }
        if ((t & 63) == 0) { red[wv_][n][0] = vs; red[wv_][n][1] = vd; }
    }
    __syncthreads();
    if (t < 8) {
        asrc[n0 + t] = red[0][t][0] + red[1][t][0];
        adst[n0 + t] = red[0][t][1] + red[1][t][1];
    }
}

// ------ fused softmax + aggregate + bias + leakyrelu: ONE WAVE PER DST --------
// EMIT=1 writes bf16 hi (RNE) only — the AA^T GEMM is hh-only.
template<int EMIT>
__global__ __launch_bounds__(256) void gat_agg_k(
    const int* __restrict__ cnt, const int* __restrict__ csr,
    const float* __restrict__ asrc, const float* __restrict__ adst,
    const float* __restrict__ h, const float* __restrict__ bias,
    float* __restrict__ out, unsigned short* __restrict__ hi)
{
    __shared__ float wbuf[4][SLOTS];
    __shared__ int   sbuf[4][SLOTS];
    const int wv = threadIdx.x >> 6, lane = threadIdx.x & 63;
    const int d = blockIdx.x * 4 + wv;
    int deg = cnt[d]; if (deg > SLOTS) deg = SLOTS;
    const float ad = adst[d];
    const int base = d * SLOTS;

    float sm = 0.f;
    for (int j = lane; j < deg; j += 64) {
        int s = csr[base + j];
        float e = asrc[s] + ad; e = e >= 0.f ? e : NEG_ATT * e;
        float ww = __expf(e);
        wbuf[wv][j] = ww; sbuf[wv][j] = s;
        sm += ww;
    }
    #pragma unroll
    for (int off = 32; off; off >>= 1) sm += __shfl_xor(sm, off, 64);
    const float inv = 1.f / sm;

    float ax = 0.f, ay = 0.f;
    #pragma unroll 4
    for (int j = 0; j < deg; ++j) {
        float ww = wbuf[wv][j];
        int   s  = sbuf[wv][j];
        const float2 hv = *(const float2*)(h + ((size_t)s << 7) + lane * 2);
        ax = fmaf(ww, hv.x, ax);
        ay = fmaf(ww, hv.y, ay);
    }
    const float2 bv = *(const float2*)(bias + lane * 2);
    float vx = lrelu(fmaf(ax, inv, bv.x), NEG_ACT);
    float vy = lrelu(fmaf(ay, inv, bv.y), NEG_ACT);

    if (EMIT) {
        uint32_t ux = __float_as_uint(vx);
        uint32_t rhx = (ux + 0x7FFFu + ((ux >> 16) & 1u)) & 0xFFFF0000u;   // RNE
        uint32_t uy = __float_as_uint(vy);
        uint32_t rhy = (uy + 0x7FFFu + ((uy >> 16) & 1u)) & 0xFFFF0000u;
        *(uint32_t*)(hi + ((size_t)d << 7) + lane * 2) = (rhx >> 16) | (rhy & 0xFFFF0000u);
    } else {
        *(float2*)(out + ((size_t)d << 7) + lane * 2) = make_float2(vx, vy);
    }
}

// ---------------- C = A A^T, hh-only bf16 MFMA, symmetric ----------------
// Round-15 staging verbatim (BK=64, 2 panels, global_load_lds, pre-swizzled
// source). SINGLE CHANGE: epilogue bounce in two 32-row halves (8 KB/wave T)
// -> total LDS 32 KB + __launch_bounds__(256,4) -> 4 blocks/CU (was 2), so
// C-store drains overlap other blocks' MFMA/staging. This also bisects the
// round-8/11 failure: if THIS fails, the halved epilogue was the bug.
__global__ __launch_bounds__(256, 4) void aat_mfma_k(
    const unsigned short* __restrict__ hi, float* __restrict__ C)
{
    __shared__ __align__(16) unsigned char smraw[32768];
    unsigned short* sm = (unsigned short*)smraw;   // 2 panels of 128x64 bf16 (32 KB)
    const int t = threadIdx.x;
    const int lane = t & 63, wv = t >> 6;

    int b = blockIdx.x;
    int ti, tj;
    if (b < 2016) {                      // strict lower: ti in [1,63], tj < ti
        ti = (int)((__builtin_sqrtf(8.f * b + 1.f) + 1.f) * 0.5f);
        while (ti * (ti - 1) / 2 > b) --ti;
        while ((ti + 1) * ti / 2 <= b) ++ti;
        tj = b - ti * (ti - 1) / 2;
    } else {                             // diagonal (half work) scheduled last
        ti = b - 2016; tj = ti;
    }
    const int bi = ti * 128, bj = tj * 128;

    const int wi0 = (wv >> 1) * 64, wj0 = (wv & 1) * 64;
    const int lr = lane & 15, g = lane >> 4;

    f32x4 acc[4][4] = {};

    const int gbase[2] = { bi, bj };

    for (int ks = 0; ks < 2; ++ks) {
        if (ks) __syncthreads();
        #pragma unroll
        for (int arr = 0; arr < 2; ++arr) {
            #pragma unroll
            for (int call = 0; call < 4; ++call) {
                int r0 = wv * 32 + call * 8;            // wave-uniform
                int r = r0 + (lane >> 3);
                int chunk = (lane & 7) ^ (r & 7);
                const unsigned short* gp = hi
                    + (size_t)(gbase[arr] + r) * HID + ks * 64 + chunk * 8;
                unsigned short* lp = sm + arr * 8192 + r0 * 64;  // uniform base
                GLD_LDS16(gp, lp);
            }
        }
        __syncthreads();   // drains vmcnt

        #pragma unroll
        for (int kw = 0; kw < 2; ++kw) {
            bf16x8 ah[4], bh[4];
            #pragma unroll
            for (int f = 0; f < 4; ++f) {
                int rA = wi0 + f * 16 + lr;
                int csA = (kw * 4 + g) ^ (rA & 7);
                ah[f] = *(const bf16x8*)(sm + 0 * 8192 + rA * 64 + csA * 8);
                int rB = wj0 + f * 16 + lr;
                int csB = (kw * 4 + g) ^ (rB & 7);
                bh[f] = *(const bf16x8*)(sm + 1 * 8192 + rB * 64 + csB * 8);
            }
            #pragma unroll
            for (int fi = 0; fi < 4; ++fi)
                #pragma unroll
                for (int fj = 0; fj < 4; ++fj)
                    acc[fi][fj] = __builtin_amdgcn_mfma_f32_16x16x32_bf16(ah[fi], bh[fj], acc[fi][fj], 0, 0, 0);
        }
    }

    __syncthreads();                       // panels dead for all waves
    float* T = (float*)smraw + wv * 2048;  // per-wave 32x64 f32 (8 KB), XOR swizzle

    // ---- direct tile, two 32-row halves (same-wave DS ordering between halves)
    #pragma unroll
    for (int hh = 0; hh < 2; ++hh) {
        #pragma unroll
        for (int fi = 2 * hh; fi < 2 * hh + 2; ++fi)
            #pragma unroll
            for (int fj = 0; fj < 4; ++fj)
                #pragma unroll
                for (int q = 0; q < 4; ++q) {
                    int row = fi * 16 + g * 4 + q - 32 * hh;   // 0..31
                    int chunk = (fj * 4 + (lr >> 2)) ^ (row & 15);
                    T[row * 64 + chunk * 4 + (lr & 3)] = acc[fi][fj][q];
                }
        #pragma unroll
        for (int it = 0; it < 8; ++it) {
            int row = it * 4 + g;
            f32x4 v = *(const f32x4*)(T + row * 64 + ((lr ^ (row & 15)) << 2));
            *(f32x4*)(C + (size_t)(bi + wi0 + 32 * hh + row) * N_NODES + bj + wj0 + lr * 4) = v;
        }
    }

    // ---- mirror tile (transpose), two 32-row halves
    if (ti != tj) {
        #pragma unroll
        for (int hh = 0; hh < 2; ++hh) {
            #pragma unroll
            for (int fi = 0; fi < 4; ++fi)
                #pragma unroll
                for (int fj = 2 * hh; fj < 2 * hh + 2; ++fj) {
                    int mrow = (fj - 2 * hh) * 16 + lr;        // 0..31
                    int chunk = (fi * 4 + g) ^ (mrow & 15);
                    *(f32x4*)(T + mrow * 64 + chunk * 4) = acc[fi][fj];
                }
            #pragma unroll
            for (int it = 0; it < 8; ++it) {
                int r = it * 4 + g;
                f32x4 v = *(const f32x4*)(T + r * 64 + ((lr ^ (r & 15)) << 2));
                *(f32x4*)(C + (size_t)(bj + wj0 + 32 * hh + r) * N_NODES + bi + wi0 + lr * 4) = v;
            }
        }
    }
}

extern "C" void kernel_launch(void* const* d_in, const int* in_sizes, int n_in,
                              void* d_out, int out_size, void* d_ws, size_t ws_size,
                              hipStream_t stream)
{
    const float* x   = (const float*)d_in[0];
    const int*   ei  = (const int*)d_in[1];
    const float* W1  = (const float*)d_in[2];
    const float* a1s = (const float*)d_in[3];
    const float* a1d = (const float*)d_in[4];
    const float* b1  = (const float*)d_in[5];
    const float* W2  = (const float*)d_in[6];
    const float* a2s = (const float*)d_in[7];
    const float* a2d = (const float*)d_in[8];
    const float* b2  = (const float*)d_in[9];
    float* C = (float*)d_out;

    // workspace layout (~15 MB)
    char* base = (char*)d_ws;
    float* h    = (float*)base;                          // 4 MB
    float* act  = (float*)(base + (4u  << 20));          // 4 MB
    int*   csr  = (int*)  (base + (8u  << 20));          // 4 MB (8192 x 128)
    int*   cnt  = (int*)  (base + (12u << 20));          // 32 KB
    float* asrc = (float*)(base + (12u << 20) + (64u << 10));
    float* adst = (float*)(base + (12u << 20) + (96u << 10));
    unsigned short* hi = (unsigned short*)(base + (13u << 20)); // 2 MB

    const int eb = (ET + 255) / 256;

    // layer 1 linear (also zeroes cnt), then adjacency build, then aggregate
    linear_alpha_k<<<N_NODES / 8, 128, 0, stream>>>(x, W1, a1s, a1d, h, asrc, adst, IN_DIM, cnt);
    append_k<<<eb, 256, 0, stream>>>(ei, cnt, csr);
    gat_agg_k<0><<<N_NODES / 4, 256, 0, stream>>>(cnt, csr, asrc, adst, h, b1, act, nullptr);
    // layer 2 (emits bf16 hi directly)
    linear_alpha_k<<<N_NODES / 8, 128, 0, stream>>>(act, W2, a2s, a2d, h, asrc, adst, HID, nullptr);
    gat_agg_k<1><<<N_NODES / 4, 256, 0, stream>>>(cnt, csr, asrc, adst, h, b2, nullptr, hi);

    // pred = act2 @ act2^T (hh-only): strict-lower pairs first, diagonals last
    aat_mfma_k<<<64 * 65 / 2, 256, 0, stream>>>(hi, C);
}